// Round 7
// baseline (211.711 us; speedup 1.0000x reference)
//
#include <hip/hip_runtime.h>
#include <hip/hip_bf16.h>

// LocalCorrelation via MFMA, round 7: wave-local waits, no block-wide drains.
// out[b, di*13+dj, h, w] = (1/16) * sum_c zt[b,c,h,w] * zt1[b,c,h+di-6,w+dj-6]
// B=8 C=256 H=W=128, 13x13 taps, zero-padded.
//
// Block = 8x8 p-tile, 512 thr = 8 waves = 4 p-patches x 2 q-halves; q-region
// 20x20 = 400 px. mfma_f32_16x16x32_bf16, acc = 8 x f32x4 = 32 VGPR.
// Phase = 16 channels (16 phases): B staged global->reg (<=16 dwords/thread,
// clamped addr + AND-mask at pack) -> pack to bf16 pixel-major frag LDS.
// Frag dbuf = 2 x 25.6KB; one 8-wave barrier per phase; MFMA after odd
// phases sits between barriers => dbuf race-free with a single barrier.
// vmcnt(0) is WAVE-LOCAL (own register loads only, issued one phase earlier
// => ~full phase of flight); asm "memory" fences + sched_barrier(0) prevent
// the R3 load-sinking disease. 51.2KB LDS + <=128 VGPR -> 2 blocks/CU,
// 16 independent waves/CU to fill each other's stalls.
// Fragment geometry, XOR slot swizzle, A-in-reg, epilogue: verbatim R2-R6
// (HW-verified, absmax 0.031).

#define HH 128
#define WW 128
#define CCT 256
#define NT 169
#define KHALF 85
#define OSTR 68
#define FRAGSZ 25600           // 400 px * 64 B (32ch bf16 per px)
#define CHPL (HH*WW)

typedef __attribute__((ext_vector_type(8))) short bf16x8;
typedef __attribute__((ext_vector_type(4))) float f32x4;

union SMEM { char raw[2*FRAGSZ]; float outb[KHALF*OSTR]; };   // 51200 B

static __device__ __forceinline__ unsigned pk2(float a, float b) {
    __hip_bfloat162 h = __float22bfloat162_rn(make_float2(a, b));
    union { __hip_bfloat162 h2; unsigned u; } c; c.h2 = h; return c.u;
}

__global__ __launch_bounds__(512, 4)
void lc7(const float* __restrict__ zt, const float* __restrict__ zt1,
         float* __restrict__ out) {
    __shared__ SMEM sm;
    char* smb = sm.raw;
    const int tid = threadIdx.x, lane = tid & 63, wid = tid >> 6;
    const int bid = blockIdx.x;
    const int b = bid & 7, t = bid >> 3;          // one batch per XCD
    const int h0 = (t >> 4) * 8, w0 = (t & 15) * 8;

    const int pw = wid & 3, qh = wid >> 2;        // p-patch, q-half
    const int py0 = (pw >> 1) * 4, px0 = (pw & 1) * 4;
    const int nlo = lane & 3, nhi = (lane >> 2) & 3, oo = lane >> 4;

    // ---- B staging descriptors: 800 units/phase (unit = 1 px x 8 ch).
    //      thread owns u0 = tid (all), u1 = 512+tid (tid < 288).
    const float* usrc[2];
    unsigned umask[2];
    int woff[2];                                  // px*64 + even-phase slot*16
    const bool act1 = tid < 288;
#pragma unroll
    for (int s = 0; s < 2; ++s) {
        const int u = tid + s * 512;
        const int o = u / 400, px = u % 400;
        const int qy = px / 20, qx = px % 20;
        const int gy = h0 + qy - 6, gx = w0 + qx - 6;
        const bool val = (gy >= 0) && (gy < HH) && (gx >= 0) && (gx < WW);
        const int cgy = val ? gy : 0, cgx = val ? gx : 0;
        usrc[s]  = zt1 + (((size_t)(b * CCT + o * 8) * HH + cgy) * WW + cgx);
        umask[s] = val ? 0xFFFFFFFFu : 0u;
        woff[s]  = px * 64 + ((o ^ ((qx + qy) & 3)) << 4);
        // odd-phase slot = (2+o)^sx = even-slot ^ 2  ->  byte ^ 32
    }

    // ---- MFMA B-frag base (R2-verified geometry; swizzle lane-constant) ----
    const int sxl = (px0 + nlo + py0 + nhi) & 3;
    const int boffb = ((py0 + nhi) * 20 + (px0 + nlo)) * 64 + ((oo ^ sxl) << 4)
                      + qh * 10240;   // + (jj>>2)*5120 + (jj&3)*256 immediates

    // ---- A-operand: global->reg once, pack to bf16 (32 VGPR) ----
    bf16x8 abf[8];
    {
        const float* ap = zt + (((size_t)(b * CCT + oo * 8) * HH + (h0 + py0 + nhi)) * WW
                                + (w0 + px0 + nlo));
#pragma unroll
        for (int p = 0; p < 8; ++p) {
            float a8[8];
#pragma unroll
            for (int e = 0; e < 8; ++e) a8[e] = ap[(size_t)(p * 32 + e) * CHPL];
            union { unsigned u[4]; bf16x8 v; } au;
            au.u[0] = pk2(a8[0], a8[1]); au.u[1] = pk2(a8[2], a8[3]);
            au.u[2] = pk2(a8[4], a8[5]); au.u[3] = pk2(a8[6], a8[7]);
            abf[p] = au.v;
        }
    }

    f32x4 acc[8];
#pragma unroll
    for (int j = 0; j < 8; ++j) acc[j] = (f32x4){0.f, 0.f, 0.f, 0.f};

    float pf[2][8];

#define LOADB() do {                                                          \
    _Pragma("unroll")                                                         \
    for (int e = 0; e < 8; ++e) pf[0][e] = usrc[0][e * CHPL];                 \
    usrc[0] += 16 * CHPL;                                                     \
    if (act1) {                                                               \
        _Pragma("unroll")                                                     \
        for (int e = 0; e < 8; ++e) pf[1][e] = usrc[1][e * CHPL];             \
    }                                                                         \
    usrc[1] += 16 * CHPL;                                                     \
} while (0)

#define PACKB(HC) do {                                                        \
    _Pragma("unroll")                                                         \
    for (int s = 0; s < 2; ++s) {                                             \
        if (s == 0 || act1) {                                                 \
            uint4 q;                                                          \
            q.x = pk2(pf[s][0], pf[s][1]) & umask[s];                         \
            q.y = pk2(pf[s][2], pf[s][3]) & umask[s];                         \
            q.z = pk2(pf[s][4], pf[s][5]) & umask[s];                         \
            q.w = pk2(pf[s][6], pf[s][7]) & umask[s];                         \
            *(uint4*)(smb + (((HC) >> 1) & 1) * FRAGSZ                        \
                      + (woff[s] ^ (((HC) & 1) << 5))) = q;                   \
        }                                                                     \
    }                                                                         \
} while (0)

#define DOMFMA(P) do {                                                        \
    const char* fb = smb + ((P) & 1) * FRAGSZ + boffb;                        \
    _Pragma("unroll")                                                         \
    for (int jj = 0; jj < 8; ++jj) {                                          \
        const bf16x8 bfr = *(const bf16x8*)(fb + (jj >> 2) * 5120 + (jj & 3) * 256); \
        acc[jj] = __builtin_amdgcn_mfma_f32_16x16x32_bf16(abf[P], bfr, acc[jj], 0, 0, 0); \
    }                                                                         \
} while (0)

    // ---- main loop: 16 phases, ONE barrier each, wave-local vmcnt ----
    LOADB();                       // phase 0 loads
#pragma unroll
    for (int hc = 0; hc < 16; ++hc) {
        asm volatile("s_waitcnt vmcnt(0)" ::: "memory");   // own loads only
        __builtin_amdgcn_sched_barrier(0);
        PACKB(hc);
        if (hc < 15) LOADB();      // next phase's loads: fly across barrier+MFMA
        asm volatile("s_waitcnt lgkmcnt(0)\n\ts_barrier" ::: "memory");
        if (hc & 1) DOMFMA(hc >> 1);   // between barriers -> dbuf race-free
    }

    // ---- epilogue (R5/R6-verified): stage k-planes through LDS ----
    // C/D: n = lane&15 (q-px), m = oo*4 + r -> py = py0+oo, px = px0+r
    const int psb = (py0 + oo) * 8 + px0;
#pragma unroll 1
    for (int pass = 0; pass < 2; ++pass) {
        const int kb = pass * KHALF;
        const int nk = pass ? (NT - KHALF) : KHALF;   // 85 / 84
        __syncthreads();
#pragma unroll
        for (int jj = 0; jj < 8; ++jj) {
            const int qi = qh * 8 + jj;
            const int di = 4 * (qi >> 2) + nhi - oo;
            const bool diok = (unsigned)di <= 12u;
            const int dib = di * 13;
#pragma unroll
            for (int r = 0; r < 4; ++r) {
                const int dj = 4 * (qi & 3) + nlo - r;
                const int k  = dib + dj;
                if (diok && (unsigned)dj <= 12u && k >= kb && k < kb + nk)
                    sm.outb[(k - kb) * OSTR + psb + r] = acc[jj][r] * 0.0625f;
            }
        }
        __syncthreads();
        const int total4 = nk * 16;
        for (int i = tid; i < total4; i += 512) {
            const int row = i >> 4, j = i & 15;
            const float4 val = *(const float4*)&sm.outb[row * OSTR + j * 4];
            float* dst = out + (((size_t)(b * NT + kb + row) * HH + h0 + (j >> 1)) * WW
                                + w0 + (j & 1) * 4);
            *(float4*)dst = val;
        }
    }
}

extern "C" void kernel_launch(void* const* d_in, const int* in_sizes, int n_in,
                              void* d_out, int out_size, void* d_ws, size_t ws_size,
                              hipStream_t stream) {
    const float* zt  = (const float*)d_in[0];
    const float* zt1 = (const float*)d_in[1];
    float* out = (float*)d_out;
    lc7<<<dim3(2048), dim3(512), 0, stream>>>(zt, zt1, out);
}